// Round 5
// baseline (302.866 us; speedup 1.0000x reference)
//
#include <hip/hip_runtime.h>
#include <stdint.h>

#define SEQ   4096
#define NDIM  768
#define HD    64
#define NH    12
#define NBH   24        // 2 * 12
#define MTOT  8192      // 2 * 4096

typedef short s8v __attribute__((ext_vector_type(8)));     // 8 bf16 (as shorts), 16B
typedef float f4v __attribute__((ext_vector_type(4)));
typedef float f16x __attribute__((ext_vector_type(16)));
typedef unsigned short u16;
typedef u16 u16x4 __attribute__((ext_vector_type(4)));
typedef uint32_t u32x4v __attribute__((ext_vector_type(4)));
typedef int i32x2 __attribute__((ext_vector_type(2)));

// SCALE * log2(e): folded into Q at the QKV epilogue.
#define C1 0.18033688011112042f

__device__ __forceinline__ u16 f2bf(float f) {             // RNE fp32 -> bf16
  union { float f; uint32_t u; } cv; cv.f = f;
  const uint32_t u = cv.u;
  return (u16)((u + 0x7fffu + ((u >> 16) & 1u)) >> 16);
}
__device__ __forceinline__ float ex2(float x) { return __builtin_amdgcn_exp2f(x); }

// packed fp32x2 -> bf16x2 (one instr, RNE; low half = first arg)
__device__ __forceinline__ uint32_t cvtpk_bf16(float lo, float hi) {
  uint32_t r;
  asm("v_cvt_pk_bf16_f32 %0, %1, %2" : "=v"(r) : "v"(lo), "v"(hi));
  return r;
}
// v_permlane32_swap_b32: swaps a's high 32 lanes with b's low 32 lanes.
__device__ __forceinline__ void pl32swap(uint32_t& a, uint32_t& b) {
  i32x2 r = __builtin_amdgcn_permlane32_swap((int)a, (int)b, false, false);
  a = (uint32_t)r.x; b = (uint32_t)r.y;
}
// async global->LDS, 16B per lane. LDS dest = wave-uniform base + lane*16B;
// global src is per-lane. __syncthreads() drains vmcnt -> data visible.
__device__ __forceinline__ void gload_lds16(const void* g, void* l) {
  __builtin_amdgcn_global_load_lds(
      (const __attribute__((address_space(1))) uint32_t*)g,
      (__attribute__((address_space(3))) uint32_t*)l, 16, 0, 0);
}

// ---------------- fp32 -> bf16 convert: all 3 arrays in ONE launch ----------------
__global__ __launch_bounds__(256) void cvt3_kernel(
    const float* __restrict__ a, u16* __restrict__ da, int na4,
    const float* __restrict__ b, u16* __restrict__ db, int nb4,
    const float* __restrict__ c, u16* __restrict__ dc, int nc4) {
  int i = blockIdx.x * 256 + threadIdx.x;
  const float* s; u16* d;
  if (i < na4)             { s = a; d = da; }
  else if (i < na4 + nb4)  { s = b; d = db; i -= na4; }
  else if (i < na4 + nb4 + nc4) { s = c; d = dc; i -= na4 + nb4; }
  else return;
  const float4 f = ((const float4*)s)[i];
  u16x4 r;
  r[0] = f2bf(f.x); r[1] = f2bf(f.y); r[2] = f2bf(f.z); r[3] = f2bf(f.w);
  ((u16x4*)d)[i] = r;
}

// ---------------- QKV GEMM: C[8192,2304] = x @ qkv_w^T + b, scattered epilogue ----
// m97-style staging (R4-verified): global_load_lds width=16 into linear
// [128][32]-u16 panels, both-sides chunk swizzle (rule #21).
__global__ __launch_bounds__(256) void gemm_qkv(const u16* __restrict__ A,
    const u16* __restrict__ B, const float* __restrict__ bias,
    u16* __restrict__ qg, u16* __restrict__ kg, u16* __restrict__ vtg) {
  __shared__ __align__(16) u16 at[128 * 32];
  __shared__ __align__(16) u16 bt[128 * 32];
  const int tid  = threadIdx.x;
  const int lane = tid & 63;
  const int w    = tid >> 6;
  const int quad = lane >> 4;
  const int col  = lane & 15;
  const int m0 = blockIdx.y * 128;
  const int n0 = blockIdx.x * 128;
  const int srow = tid >> 2;                         // 0..63
  const int schk = ((tid & 3) ^ (srow & 3)) * 8;     // swizzled source chunk
  const int wm = (w >> 1) * 64;
  const int wn = (w & 1) * 64;
  const int xq = (quad ^ (col & 3)) * 8;             // swizzled read slot

  const f4v fz = {0.f, 0.f, 0.f, 0.f};
  f4v acc[4][4];
#pragma unroll
  for (int i = 0; i < 4; i++)
#pragma unroll
    for (int j = 0; j < 4; j++) acc[i][j] = fz;

  const u16* ga0 = A + (size_t)(m0 + srow) * NDIM + schk;
  const u16* ga1 = A + (size_t)(m0 + 64 + srow) * NDIM + schk;
  const u16* gb0 = B + (size_t)(n0 + srow) * NDIM + schk;
  const u16* gb1 = B + (size_t)(n0 + 64 + srow) * NDIM + schk;
  u16* const la = at + (size_t)w * 512;
  u16* const lb = bt + (size_t)w * 512;

  for (int k0 = 0; k0 < NDIM; k0 += 32) {
    __syncthreads();                  // prior compute done reading LDS
    gload_lds16(ga0 + k0, la);
    gload_lds16(ga1 + k0, la + 2048);
    gload_lds16(gb0 + k0, lb);
    gload_lds16(gb1 + k0, lb + 2048);
    __syncthreads();                  // vmcnt drained -> tiles in LDS
    s8v af[4], bf[4];
#pragma unroll
    for (int i = 0; i < 4; i++)
      af[i] = *(const s8v*)(at + (wm + i * 16 + col) * 32 + xq);
#pragma unroll
    for (int j = 0; j < 4; j++)
      bf[j] = *(const s8v*)(bt + (wn + j * 16 + col) * 32 + xq);
#pragma unroll
    for (int i = 0; i < 4; i++)
#pragma unroll
      for (int j = 0; j < 4; j++)
        acc[i][j] = __builtin_amdgcn_mfma_f32_16x16x32_bf16(af[i], bf[j], acc[i][j], 0, 0, 0);
  }

  const int wmg = m0 + wm;
  const int wng = n0 + wn;
  const int s = n0 / NDIM;   // 0=q 1=k 2=v, block-uniform (768 = 6*128)
#pragma unroll
  for (int j = 0; j < 4; j++) {
    const int c = wng + j * 16 + col;
    const float bv = bias[c];
    const int r = c - s * NDIM;
    const int h = r >> 6;
    const int d = r & 63;
#pragma unroll
    for (int i = 0; i < 4; i++) {
      const int mb = wmg + i * 16 + quad * 4;   // 4 consecutive rows (regs)
      const int bb = mb >> 12;
      const int n  = mb & 4095;
      const size_t hb = (size_t)(bb * NH + h);
      const f4v v = acc[i][j];
      if (s == 2) {
        u16x4 pk;
#pragma unroll
        for (int rg = 0; rg < 4; rg++) pk[rg] = f2bf(v[rg] + bv);
        *(u16x4*)(vtg + (hb * HD + d) * SEQ + n) = pk;   // transposed store
      } else if (s == 0) {
#pragma unroll
        for (int rg = 0; rg < 4; rg++)
          qg[(hb * SEQ + (size_t)(n + rg)) * HD + d] = f2bf((v[rg] + bv) * C1);
      } else {
#pragma unroll
        for (int rg = 0; rg < 4; rg++)
          kg[(hb * SEQ + (size_t)(n + rg)) * HD + d] = f2bf(v[rg] + bv);
      }
    }
  }
}

// ---------------- flash attention: (q-half x key-half) wave split ----------------
// LDS-pipe theory (R4 counters): 66% LDS busy from redundant frag reads --
// all 4 waves read the SAME K/V frags (1 read : 1 MFMA). New split: wave w
// owns q-half (w>>1) x key-half (w&1): each K-frag read feeds both q-halves'
// QK MFMAs, each V-frag read feeds both q-halves' PV -> LDS reads/block-iter
// 64 -> 32. Staging via global_load_lds into linear [64][64] panels with the
// m214 XOR swizzle ((row&7) slot xor), swizzle on SOURCE addr + READ offset
// (both-sides, rule #21) -> zero staging VGPRs/ds_writes. One-time cross-wave
// O/l merge through smem at loop end combines the two key-halves.
__global__ __launch_bounds__(256, 2) void attn_kernel(const u16* __restrict__ qg,
    const u16* __restrict__ kg, const u16* __restrict__ vtg, u16* __restrict__ og) {
  __shared__ __align__(16) u16 smem[2][2][4096];   // [buf][0=K,1=V][64 rows x 64]
  __shared__ float lred[2][64];                    // [q-pair][q_local] partials/inv

  const int tid  = threadIdx.x;
  const int lane = tid & 63;
  const int w    = tid >> 6;
  const int hi   = lane >> 5;
  const int c    = lane & 31;
  const int kth  = w & 1;            // this wave's key half (0: keys 0..31)
  const int pair = w >> 1;           // q half: 0 -> q 0..63, 1 -> q 64..127
  // XCD swizzle: bh = blk % 24 -> all q-tiles of one (b,h) on one XCD.
  const int blk = blockIdx.x;
  const int bh  = blk % NBH;
  const int q0  = (blk / NBH) * 128;
  const size_t gbase = (size_t)bh * (SEQ * HD);
  const int qw = pair * 64;

  // Q B-frags (loop-invariant): qfA = q rows qw+c, qfB = q rows qw+32+c
  s8v qfA[4], qfB[4];
#pragma unroll
  for (int s = 0; s < 4; s++) {
    qfA[s] = *(const s8v*)(qg + gbase + (size_t)(q0 + qw + c) * HD + s * 16 + hi * 8);
    qfB[s] = *(const s8v*)(qg + gbase + (size_t)(q0 + qw + 32 + c) * HD + s * 16 + hi * 8);
  }

  f16x zacc;                         // persistent zero C-operand (st init hoist)
#pragma unroll
  for (int e = 0; e < 16; e++) zacc[e] = 0.f;
  f16x o00 = zacc, o01 = zacc, o10 = zacc, o11 = zacc;  // o[qt][dt]
  float l0a = 0.f, l1a = 0.f, l2a = 0.f, l3a = 0.f;     // l partials qt=0
  float l0b = 0.f, l1b = 0.f, l2b = 0.f, l3b = 0.f;     // l partials qt=1

  // staging (global_load_lds): wave w stages K rows [w*16,w*16+16) and V same.
  // lane L -> row lrow=L>>3, phys slot L&7; source slot = (L&7)^lrow so that
  // LDS phys slot p of row r holds logical slot p^(r&7).
  const int lrow  = lane >> 3;
  const int lslot = (lane & 7) ^ lrow;
  const u16* kgl0 = kg  + gbase + (size_t)(w * 16 + lrow) * HD  + lslot * 8;
  const u16* kgl1 = kgl0 + (size_t)8 * HD;
  const u16* vgl0 = vtg + gbase + (size_t)(w * 16 + lrow) * SEQ + lslot * 8;
  const u16* vgl1 = vgl0 + (size_t)8 * SEQ;

  // prologue: stage tile 0 into buf 0 (first loop barrier drains it)
  {
    u16* kd = (u16*)smem[0][0] + w * 1024;
    u16* vd = (u16*)smem[0][1] + w * 1024;
    gload_lds16(kgl0, kd);
    gload_lds16(kgl1, kd + 512);
    gload_lds16(vgl0, vd);
    gload_lds16(vgl1, vd + 512);
  }

  // frag read offset components (u16 units)
  const int kbase = kth * 2048 + c * 64;        // key row = kth*32 + c
  const int c7 = c & 7;

  for (int kb = 0; kb < SEQ; kb += 64) {
    const int cur = (kb >> 6) & 1;
    const u16* kb_ = smem[cur][0];
    const u16* vb_ = smem[cur][1];
    __syncthreads();                 // drains prev gloads; buf[cur] ready

    // issue next-tile DMA into buf[cur^1]; next barrier drains it
    if (kb + 64 < SEQ) {
      const int nb = cur ^ 1;
      u16* kd = (u16*)smem[nb][0] + w * 1024;
      u16* vd = (u16*)smem[nb][1] + w * 1024;
      gload_lds16(kgl0 + (size_t)(kb + 64) * HD, kd);
      gload_lds16(kgl1 + (size_t)(kb + 64) * HD, kd + 512);
      gload_lds16(vgl0 + (kb + 64), vd);
      gload_lds16(vgl1 + (kb + 64), vd + 512);
    }

    // QK: sA/sB = K(kth half) @ Q^T for q-halves A/B. 4 reads feed 8 MFMAs.
    __builtin_amdgcn_s_setprio(1);
    f16x sA, sB;
    {
      const s8v kf0 = *(const s8v*)(kb_ + kbase + ((((0 * 2 + hi)) ^ c7) << 3));
      sA = __builtin_amdgcn_mfma_f32_32x32x16_bf16(kf0, qfA[0], zacc, 0, 0, 0);
      sB = __builtin_amdgcn_mfma_f32_32x32x16_bf16(kf0, qfB[0], zacc, 0, 0, 0);
      const s8v kf1 = *(const s8v*)(kb_ + kbase + ((((1 * 2 + hi)) ^ c7) << 3));
      sA = __builtin_amdgcn_mfma_f32_32x32x16_bf16(kf1, qfA[1], sA, 0, 0, 0);
      sB = __builtin_amdgcn_mfma_f32_32x32x16_bf16(kf1, qfB[1], sB, 0, 0, 0);
      const s8v kf2 = *(const s8v*)(kb_ + kbase + ((((2 * 2 + hi)) ^ c7) << 3));
      sA = __builtin_amdgcn_mfma_f32_32x32x16_bf16(kf2, qfA[2], sA, 0, 0, 0);
      sB = __builtin_amdgcn_mfma_f32_32x32x16_bf16(kf2, qfB[2], sB, 0, 0, 0);
      const s8v kf3 = *(const s8v*)(kb_ + kbase + ((((3 * 2 + hi)) ^ c7) << 3));
      sA = __builtin_amdgcn_mfma_f32_32x32x16_bf16(kf3, qfA[3], sA, 0, 0, 0);
      sB = __builtin_amdgcn_mfma_f32_32x32x16_bf16(kf3, qfB[3], sB, 0, 0, 0);
    }
    __builtin_amdgcn_s_setprio(0);

    // SM(sA) -> pa00, pa01 (key slices 0..15 / 16..31 of this wave's half)
    s8v pa00, pa01, pa10, pa11;
    {
      float p[16];
#pragma unroll
      for (int e = 0; e < 16; e++) p[e] = ex2(sA[e]);
      l0a += p[0] + p[4] + p[8]  + p[12];
      l1a += p[1] + p[5] + p[9]  + p[13];
      l2a += p[2] + p[6] + p[10] + p[14];
      l3a += p[3] + p[7] + p[11] + p[15];
      uint32_t k0 = cvtpk_bf16(p[0],  p[1]);
      uint32_t k1 = cvtpk_bf16(p[2],  p[3]);
      uint32_t k2 = cvtpk_bf16(p[4],  p[5]);
      uint32_t k3 = cvtpk_bf16(p[6],  p[7]);
      uint32_t k4 = cvtpk_bf16(p[8],  p[9]);
      uint32_t k5 = cvtpk_bf16(p[10], p[11]);
      uint32_t k6 = cvtpk_bf16(p[12], p[13]);
      uint32_t k7 = cvtpk_bf16(p[14], p[15]);
      pl32swap(k0, k2); pl32swap(k1, k3);
      pl32swap(k4, k6); pl32swap(k5, k7);
      u32x4v wA = {k0, k1, k2, k3};
      u32x4v wB = {k4, k5, k6, k7};
      pa00 = __builtin_bit_cast(s8v, wA);
      pa01 = __builtin_bit_cast(s8v, wB);
    }

    // PV-A: read the 4 V-frags (kept for PV-B), accumulate q-half A
    s8v vf0, vf1, vf2, vf3;          // [j][dt]: j = key slice, dt = d half
    __builtin_amdgcn_s_setprio(1);
    {
      vf0 = *(const s8v*)(vb_ + 0 * 2048 + c * 64 + (((kth * 4 + 0 + hi) ^ c7) << 3));
      vf1 = *(const s8v*)(vb_ + 1 * 2048 + c * 64 + (((kth * 4 + 0 + hi) ^ c7) << 3));
      vf2 = *(const s8v*)(vb_ + 0 * 2048 + c * 64 + (((kth * 4 + 2 + hi) ^ c7) << 3));
      vf3 = *(const s8v*)(vb_ + 1 * 2048 + c * 64 + (((kth * 4 + 2 + hi) ^ c7) << 3));
      o00 = __builtin_amdgcn_mfma_f32_32x32x16_bf16(pa00, vf0, o00, 0, 0, 0);
      o01 = __builtin_amdgcn_mfma_f32_32x32x16_bf16(pa00, vf1, o01, 0, 0, 0);
      o00 = __builtin_amdgcn_mfma_f32_32x32x16_bf16(pa01, vf2, o00, 0, 0, 0);
      o01 = __builtin_amdgcn_mfma_f32_32x32x16_bf16(pa01, vf3, o01, 0, 0, 0);
    }
    __builtin_amdgcn_s_setprio(0);

    // SM(sB) -> pa10, pa11 (overlaps PV-A MFMAs)
    {
      float p[16];
#pragma unroll
      for (int e = 0; e < 16; e++) p[e] = ex2(sB[e]);
      l0b += p[0] + p[4] + p[8]  + p[12];
      l1b += p[1] + p[5] + p[9]  + p[13];
      l2b += p[2] + p[6] + p[10] + p[14];
      l3b += p[3] + p[7] + p[11] + p[15];
      uint32_t k0 = cvtpk_bf16(p[0],  p[1]);
      uint32_t k1 = cvtpk_bf16(p[2],  p[3]);
      uint32_t k2 = cvtpk_bf16(p[4],  p[5]);
      uint32_t k3 = cvtpk_bf16(p[6],  p[7]);
      uint32_t k4 = cvtpk_bf16(p[8],  p[9]);
      uint32_t k5 = cvtpk_bf16(p[10], p[11]);
      uint32_t k6 = cvtpk_bf16(p[12], p[13]);
      uint32_t k7 = cvtpk_bf16(p[14], p[15]);
      pl32swap(k0, k2); pl32swap(k1, k3);
      pl32swap(k4, k6); pl32swap(k5, k7);
      u32x4v wA = {k0, k1, k2, k3};
      u32x4v wB = {k4, k5, k6, k7};
      pa10 = __builtin_bit_cast(s8v, wA);
      pa11 = __builtin_bit_cast(s8v, wB);
    }

    // PV-B: q-half B from the held V-frags (zero extra LDS reads)
    __builtin_amdgcn_s_setprio(1);
    {
      o10 = __builtin_amdgcn_mfma_f32_32x32x16_bf16(pa10, vf0, o10, 0, 0, 0);
      o11 = __builtin_amdgcn_mfma_f32_32x32x16_bf16(pa10, vf1, o11, 0, 0, 0);
      o10 = __builtin_amdgcn_mfma_f32_32x32x16_bf16(pa11, vf2, o10, 0, 0, 0);
      o11 = __builtin_amdgcn_mfma_f32_32x32x16_bf16(pa11, vf3, o11, 0, 0, 0);
    }
    __builtin_amdgcn_s_setprio(0);
  }

  // ---- cross-wave merge: key-half 1 waves ship O,l; key-half 0 waves reduce ----
  float* M  = (float*)smem + pair * 4096;   // 64q x 64d f32 scratch per pair
  float* LP = lred[pair];
  float ltA = l0a + l1a + l2a + l3a;  ltA += __shfl_xor(ltA, 32);
  float ltB = l0b + l1b + l2b + l3b;  ltB += __shfl_xor(ltB, 32);
  __syncthreads();                   // all K/V reads of smem done
  if (kth) {
    if (hi == 0) { LP[c] = ltA; LP[32 + c] = ltB; }
#pragma unroll
    for (int r = 0; r < 16; r++) {
      const int rq = (r & 3) + 8 * (r >> 2) + 4 * hi;
      M[rq * 64 + c]             = o00[r];
      M[rq * 64 + 32 + c]        = o01[r];
      M[(32 + rq) * 64 + c]      = o10[r];
      M[(32 + rq) * 64 + 32 + c] = o11[r];
    }
  }
  __syncthreads();
  if (!kth) {
    const float invA = 1.0f / (ltA + LP[c]);
    const float invB = 1.0f / (ltB + LP[32 + c]);
    if (hi == 0) { LP[c] = invA; LP[32 + c] = invB; }   // broadcast via LDS
    const int b = bh / NH;
    const int h = bh % NH;
    u16* obase = og + (size_t)(b * SEQ + q0 + pair * 64) * NDIM + h * HD;
#pragma unroll
    for (int r = 0; r < 16; r++) {
      const int rq = (r & 3) + 8 * (r >> 2) + 4 * hi;
      const float iA = LP[rq];
      const float iB = LP[32 + rq];
      u16* r0 = obase + (size_t)rq * NDIM;
      u16* r1 = obase + (size_t)(32 + rq) * NDIM;
      r0[c]      = f2bf((o00[r] + M[rq * 64 + c]) * iA);
      r0[32 + c] = f2bf((o01[r] + M[rq * 64 + 32 + c]) * iA);
      r1[c]      = f2bf((o10[r] + M[(32 + rq) * 64 + c]) * iB);
      r1[32 + c] = f2bf((o11[r] + M[(32 + rq) * 64 + 32 + c]) * iB);
    }
  }
}

// ---------------- proj GEMM: out[8192,768] = attn @ proj_w^T + b (fp32 out) ----
// Same global_load_lds staging as gemm_qkv (R4-verified).
__global__ __launch_bounds__(256) void gemm_proj(const u16* __restrict__ A,
    const u16* __restrict__ B, const float* __restrict__ bias, float* __restrict__ out) {
  __shared__ __align__(16) u16 at[128 * 32];
  __shared__ __align__(16) u16 bt[128 * 32];
  const int tid  = threadIdx.x;
  const int lane = tid & 63;
  const int w    = tid >> 6;
  const int quad = lane >> 4;
  const int col  = lane & 15;
  const int m0 = blockIdx.y * 128;
  const int n0 = blockIdx.x * 128;
  const int srow = tid >> 2;
  const int schk = ((tid & 3) ^ (srow & 3)) * 8;
  const int wm = (w >> 1) * 64;
  const int wn = (w & 1) * 64;
  const int xq = (quad ^ (col & 3)) * 8;

  const f4v fz = {0.f, 0.f, 0.f, 0.f};
  f4v acc[4][4];
#pragma unroll
  for (int i = 0; i < 4; i++)
#pragma unroll
    for (int j = 0; j < 4; j++) acc[i][j] = fz;

  const u16* ga0 = A + (size_t)(m0 + srow) * NDIM + schk;
  const u16* ga1 = A + (size_t)(m0 + 64 + srow) * NDIM + schk;
  const u16* gb0 = B + (size_t)(n0 + srow) * NDIM + schk;
  const u16* gb1 = B + (size_t)(n0 + 64 + srow) * NDIM + schk;
  u16* const la = at + (size_t)w * 512;
  u16* const lb = bt + (size_t)w * 512;

  for (int k0 = 0; k0 < NDIM; k0 += 32) {
    __syncthreads();
    gload_lds16(ga0 + k0, la);
    gload_lds16(ga1 + k0, la + 2048);
    gload_lds16(gb0 + k0, lb);
    gload_lds16(gb1 + k0, lb + 2048);
    __syncthreads();
    s8v af[4], bf[4];
#pragma unroll
    for (int i = 0; i < 4; i++)
      af[i] = *(const s8v*)(at + (wm + i * 16 + col) * 32 + xq);
#pragma unroll
    for (int j = 0; j < 4; j++)
      bf[j] = *(const s8v*)(bt + (wn + j * 16 + col) * 32 + xq);
#pragma unroll
    for (int i = 0; i < 4; i++)
#pragma unroll
      for (int j = 0; j < 4; j++)
        acc[i][j] = __builtin_amdgcn_mfma_f32_16x16x32_bf16(af[i], bf[j], acc[i][j], 0, 0, 0);
  }

  const int wmg = m0 + wm;
  const int wng = n0 + wn;
#pragma unroll
  for (int j = 0; j < 4; j++) {
    const int c = wng + j * 16 + col;
    const float bv = bias[c];
#pragma unroll
    for (int i = 0; i < 4; i++) {
#pragma unroll
      for (int rg = 0; rg < 4; rg++)
        out[(size_t)(wmg + i * 16 + quad * 4 + rg) * NDIM + c] = acc[i][j][rg] + bv;
    }
  }
}

// ---------------- launch ----------------
extern "C" void kernel_launch(void* const* d_in, const int* in_sizes, int n_in,
                              void* d_out, int out_size, void* d_ws, size_t ws_size,
                              hipStream_t stream) {
  const float* x      = (const float*)d_in[0];
  const float* qkv_w  = (const float*)d_in[1];
  const float* qkv_b  = (const float*)d_in[2];
  const float* proj_w = (const float*)d_in[3];
  const float* proj_b = (const float*)d_in[4];
  float* out = (float*)d_out;

  u16* ws   = (u16*)d_ws;
  u16* x_bf = ws;                              // 8192*768
  u16* wq   = x_bf + (size_t)MTOT * NDIM;      // 2304*768
  u16* wp   = wq + (size_t)3 * NDIM * NDIM;    // 768*768
  u16* q_bf = wp + (size_t)NDIM * NDIM;        // 24*4096*64 each
  u16* k_bf = q_bf + (size_t)NBH * SEQ * HD;
  u16* vt   = k_bf + (size_t)NBH * SEQ * HD;
  u16* a_bf = vt + (size_t)NBH * SEQ * HD;     // 8192*768

  const int nx = MTOT * NDIM / 4, nw1 = 3 * NDIM * NDIM / 4, nw2 = NDIM * NDIM / 4;
  const int ntot = nx + nw1 + nw2;
  cvt3_kernel<<<(ntot + 255) / 256, 256, 0, stream>>>(x, x_bf, nx, qkv_w, wq, nw1,
                                                      proj_w, wp, nw2);

  gemm_qkv<<<dim3(18, 64), 256, 0, stream>>>(x_bf, wq, qkv_b, q_bf, k_bf, vt);
  attn_kernel<<<768, 256, 0, stream>>>(q_bf, k_bf, vt, a_bf);
  gemm_proj<<<dim3(6, 64), 256, 0, stream>>>(a_bf, wp, proj_b, out);
}